// Round 3
// baseline (6501.460 us; speedup 1.0000x reference)
//
#include <hip/hip_runtime.h>
#include <hip/hip_bf16.h>
#include <stdint.h>

// Problem constants (fixed by the reference)
#define HEADS 4
#define KNN   32
#define NKEYS 128
#define KDIM  256
#define VDIM  768
#define INDIM 3072
#define HALFD 128
#define NC    (VDIM + HEADS * KDIM)   // 1792 combined output cols: [dense(768) | q(1024)]

typedef __bf16 bf16x8 __attribute__((ext_vector_type(8)));
typedef short  short8 __attribute__((ext_vector_type(8)));
typedef float  f32x4  __attribute__((ext_vector_type(4)));

__device__ __forceinline__ void async_copy16(const void* g, void* l) {
    __builtin_amdgcn_global_load_lds((__attribute__((address_space(1))) void*)(g),
                                     (__attribute__((address_space(3))) void*)(l),
                                     16, 0, 0);
}

// ---------------------------------------------------------------------------
// Kernel 0: fp32 -> bf16 convert for x (one thread per 8 elements)
// ---------------------------------------------------------------------------
__global__ __launch_bounds__(256) void convert_bf16(
    const float* __restrict__ in, __hip_bfloat16* __restrict__ out, int n8)
{
    int i = blockIdx.x * 256 + threadIdx.x;
    if (i >= n8) return;
    float4 a = ((const float4*)in)[2 * i + 0];
    float4 b = ((const float4*)in)[2 * i + 1];
    union { short8 v; __hip_bfloat16 h[8]; } u;
    u.h[0] = __float2bfloat16(a.x); u.h[1] = __float2bfloat16(a.y);
    u.h[2] = __float2bfloat16(a.z); u.h[3] = __float2bfloat16(a.w);
    u.h[4] = __float2bfloat16(b.x); u.h[5] = __float2bfloat16(b.y);
    u.h[6] = __float2bfloat16(b.z); u.h[7] = __float2bfloat16(b.w);
    ((short8*)out)[i] = u.v;
}

// ---------------------------------------------------------------------------
// Kernel 1: build Bt = [W_dense | W_q]^T as (NC x INDIM) bf16, via LDS tiles
// ---------------------------------------------------------------------------
__global__ __launch_bounds__(256) void transpose_w(
    const float* __restrict__ Wd,   // (3072, 768) fp32
    const float* __restrict__ Wq,   // (3072, 1024) fp32
    __hip_bfloat16* __restrict__ Wc)// (1792, 3072) bf16
{
    __shared__ float tile[32][33];
    const int kt = blockIdx.x * 32;
    const int nt = blockIdx.y * 32;
    const int tx = threadIdx.x;   // 0..31
    const int ty = threadIdx.y;   // 0..7
    const float* src;
    int ldn, ncol;
    if (nt < VDIM) { src = Wd; ldn = VDIM; ncol = nt; }
    else           { src = Wq; ldn = HEADS * KDIM; ncol = nt - VDIM; }
#pragma unroll
    for (int j = 0; j < 32; j += 8)
        tile[ty + j][tx] = src[(size_t)(kt + ty + j) * ldn + ncol + tx];
    __syncthreads();
#pragma unroll
    for (int j = 0; j < 32; j += 8)
        Wc[(size_t)(nt + ty + j) * INDIM + kt + tx] = __float2bfloat16(tile[tx][ty + j]);
}

// ---------------------------------------------------------------------------
// Kernel 2: C(M x 1792) = A(M x 3072) @ Bt^T + bias   (bf16 MFMA, m97 structure)
// ---------------------------------------------------------------------------
__global__ __launch_bounds__(256) void gemm_bt(
    const __hip_bfloat16* __restrict__ A,   // (M, 3072) bf16
    const __hip_bfloat16* __restrict__ Bt,  // (1792, 3072) bf16
    const float* __restrict__ bd,  // (768,) fp32
    const float* __restrict__ bq,  // (1024,) fp32
    float* __restrict__ C, int M)
{
    constexpr int K = INDIM, N = NC;
    __shared__ __align__(16) __hip_bfloat16 As[128 * 32];
    __shared__ __align__(16) __hip_bfloat16 Bs[128 * 32];
    const int tid  = threadIdx.x;
    const int wave = tid >> 6, lane = tid & 63;
    const int wm = wave >> 1, wn = wave & 1;
    const int row0 = blockIdx.x * 128, col0 = blockIdx.y * 128;

    const int fb0 = (wave * 2 + 0) * 1024;
    const int fb1 = (wave * 2 + 1) * 1024;
    const int r0  = (fb0 >> 6) + (lane >> 2);
    const int r1  = (fb1 >> 6) + (lane >> 2);
    const int ce  = (lane & 3) * 8;
    const __hip_bfloat16* gA0 = A  + (size_t)(row0 + r0) * K + ce;
    const __hip_bfloat16* gA1 = A  + (size_t)(row0 + r1) * K + ce;
    const __hip_bfloat16* gB0 = Bt + (size_t)(col0 + r0) * K + ce;
    const __hip_bfloat16* gB1 = Bt + (size_t)(col0 + r1) * K + ce;
    char* lA0 = (char*)As + fb0;  char* lA1 = (char*)As + fb1;
    char* lB0 = (char*)Bs + fb0;  char* lB1 = (char*)Bs + fb1;

    const int aoff = (wm * 64 + (lane & 15)) * 64 + (lane >> 4) * 16;
    const int boff = (wn * 64 + (lane & 15)) * 64 + (lane >> 4) * 16;

    f32x4 acc[4][4];
#pragma unroll
    for (int i = 0; i < 4; i++)
#pragma unroll
        for (int j = 0; j < 4; j++) acc[i][j] = (f32x4){0.f, 0.f, 0.f, 0.f};

    for (int k0 = 0; k0 < K; k0 += 32) {
        __syncthreads();
        async_copy16(gA0 + k0, lA0);
        async_copy16(gA1 + k0, lA1);
        async_copy16(gB0 + k0, lB0);
        async_copy16(gB1 + k0, lB1);
        __syncthreads();

        bf16x8 af[4], bfr[4];
#pragma unroll
        for (int i = 0; i < 4; i++)
            af[i] = *(const bf16x8*)((const char*)As + aoff + i * 1024);
#pragma unroll
        for (int j = 0; j < 4; j++)
            bfr[j] = *(const bf16x8*)((const char*)Bs + boff + j * 1024);
#pragma unroll
        for (int i = 0; i < 4; i++)
#pragma unroll
            for (int j = 0; j < 4; j++)
                acc[i][j] = __builtin_amdgcn_mfma_f32_16x16x32_bf16(af[i], bfr[j], acc[i][j], 0, 0, 0);
    }

    float bias[4]; int ncol[4];
#pragma unroll
    for (int j = 0; j < 4; j++) {
        int n = col0 + wn * 64 + j * 16 + (lane & 15);
        ncol[j] = n;
        bias[j] = (n < VDIM) ? bd[n] : bq[n - VDIM];
    }
#pragma unroll
    for (int i = 0; i < 4; i++) {
#pragma unroll
        for (int r = 0; r < 4; r++) {
            int m = row0 + wm * 64 + i * 16 + (lane >> 4) * 4 + r;
            float* crow = C + (size_t)m * N;
#pragma unroll
            for (int j = 0; j < 4; j++) crow[ncol[j]] = acc[i][j][r] + bias[j];
        }
    }
}

// ---------------------------------------------------------------------------
// Kernel 3: PKM scoring + two-stage top-k + softmax. One wave per (token, head).
// ---------------------------------------------------------------------------
__global__ __launch_bounds__(256) void pkm_select(
    const float* __restrict__ qd,    // (M, 1792); q at cols 768..1792
    const float* __restrict__ keys,  // (4, 2, 128, 128) fp32
    float* __restrict__ w_out,       // (M, 4, 32)
    int* __restrict__ i_out)         // (M, 4, 32)
{
    const int t = blockIdx.x;
    const int tid = threadIdx.x;
    const int h = tid >> 6, lane = tid & 63;
    __shared__ __align__(16) float qs[HEADS * KDIM];  // 1024
    __shared__ float vsel[HEADS][2][KNN];
    __shared__ int   isel[HEADS][2][KNN];

    const float* qrow = qd + (size_t)t * NC + VDIM;
    for (int i = tid; i < HEADS * KDIM; i += 256) qs[i] = qrow[i];
    __syncthreads();

    // ---- scores: lane handles sub-keys n=lane and n=lane+64 for both halves
    float c0[2], c1[2];
#pragma unroll
    for (int half = 0; half < 2; ++half) {
        const float* kb = keys + (size_t)((h * 2 + half) * NKEYS) * HALFD;
        const float* qh = qs + h * KDIM + half * HALFD;
        const float* kr0 = kb + (size_t)lane * HALFD;
        const float* kr1 = kb + (size_t)(lane + 64) * HALFD;
        float a0 = 0.f, a1 = 0.f;
#pragma unroll
        for (int d = 0; d < HALFD; d += 8) {
            float4 qv0 = *(const float4*)(qh + d);
            float4 qv1 = *(const float4*)(qh + d + 4);
            float4 k00 = *(const float4*)(kr0 + d);
            float4 k01 = *(const float4*)(kr0 + d + 4);
            float4 k10 = *(const float4*)(kr1 + d);
            float4 k11 = *(const float4*)(kr1 + d + 4);
            a0 = fmaf(k00.x, qv0.x, a0); a0 = fmaf(k00.y, qv0.y, a0);
            a0 = fmaf(k00.z, qv0.z, a0); a0 = fmaf(k00.w, qv0.w, a0);
            a0 = fmaf(k01.x, qv1.x, a0); a0 = fmaf(k01.y, qv1.y, a0);
            a0 = fmaf(k01.z, qv1.z, a0); a0 = fmaf(k01.w, qv1.w, a0);
            a1 = fmaf(k10.x, qv0.x, a1); a1 = fmaf(k10.y, qv0.y, a1);
            a1 = fmaf(k10.z, qv0.z, a1); a1 = fmaf(k10.w, qv0.w, a1);
            a1 = fmaf(k11.x, qv1.x, a1); a1 = fmaf(k11.y, qv1.y, a1);
            a1 = fmaf(k11.z, qv1.z, a1); a1 = fmaf(k11.w, qv1.w, a1);
        }
        c0[half] = a0; c1[half] = a1;
    }

    // ---- top-32 of 128 per half (iterative wave argmax, tie -> lower index)
#pragma unroll
    for (int half = 0; half < 2; ++half) {
        float v0 = c0[half], v1 = c1[half];
        for (int r = 0; r < KNN; ++r) {
            float v; int idx;
            if (v0 >= v1) { v = v0; idx = lane; } else { v = v1; idx = lane + 64; }
#pragma unroll
            for (int m = 1; m < 64; m <<= 1) {
                float ov = __shfl_xor(v, m);
                int   oi = __shfl_xor(idx, m);
                if (ov > v || (ov == v && oi < idx)) { v = ov; idx = oi; }
            }
            if (lane == 0) { vsel[h][half][r] = v; isel[h][half][r] = idx; }
            if (idx == lane) v0 = -1e30f;
            else if (idx == lane + 64) v1 = -1e30f;
        }
    }
    __syncthreads();

    // ---- cartesian 32x32 -> top-32 of 1024; lane holds cands m*64+lane
    const float* v1s = vsel[h][0];
    const float* v2s = vsel[h][1];
    float cv[16];
#pragma unroll
    for (int m = 0; m < 16; ++m) {
        int cand = m * 64 + lane;
        cv[m] = v1s[cand >> 5] + v2s[cand & 31];
    }
    float selv = -1e30f; int selc = 0;
    for (int r = 0; r < KNN; ++r) {
        float v = -1e30f; int mi = 0;
#pragma unroll
        for (int m = 0; m < 16; ++m)
            if (cv[m] > v) { v = cv[m]; mi = m; }
        int cand = mi * 64 + lane;
#pragma unroll
        for (int m = 1; m < 64; m <<= 1) {
            float ov = __shfl_xor(v, m);
            int   oc = __shfl_xor(cand, m);
            if (ov > v || (ov == v && oc < cand)) { v = ov; cand = oc; }
        }
        if (lane == r) { selv = v; selc = cand; }
        int mclear = cand >> 6; int lclear = cand & 63;
#pragma unroll
        for (int m = 0; m < 16; ++m)
            if (m == mclear && lclear == lane) cv[m] = -1e30f;
    }

    // ---- softmax over the 32 selected (lanes 0..31 hold them)
    float mx = selv;
#pragma unroll
    for (int m = 16; m >= 1; m >>= 1) mx = fmaxf(mx, __shfl_xor(mx, m));
    float e = (lane < KNN) ? expf(selv - mx) : 0.f;
    float sum = e;
#pragma unroll
    for (int m = 16; m >= 1; m >>= 1) sum += __shfl_xor(sum, m);
    if (lane < KNN) {
        int i = selc >> 5, j = selc & 31;
        int big = isel[h][0][i] * NKEYS + isel[h][1][j];
        size_t o = ((size_t)t * HEADS + h) * KNN + lane;
        w_out[o] = e / sum;
        i_out[o] = big;
    }
}

// ---------------------------------------------------------------------------
// Kernel 4: value gather + dense + residual + layernorm. One block per token.
// Output is fp32 (reference output dtype).
// ---------------------------------------------------------------------------
__global__ __launch_bounds__(256) void fuse_ln(
    const float* __restrict__ qd,              // dense at cols 0..768 (bias included)
    const float* __restrict__ resid,           // (M, 768) fp32
    const float* __restrict__ values,          // (16384, 768) fp32
    const float* __restrict__ pw, const int* __restrict__ pi,  // (M,128)
    const float* __restrict__ gamma, const float* __restrict__ beta,
    float* __restrict__ out)
{
    const int t = blockIdx.x, tid = threadIdx.x;
    const int wave = tid >> 6, lane = tid & 63;
    __shared__ float ws[HEADS * KNN];
    __shared__ int   is_[HEADS * KNN];
    __shared__ float red[8];
    if (tid < HEADS * KNN) {
        ws[tid]  = pw[(size_t)t * (HEADS * KNN) + tid];
        is_[tid] = pi[(size_t)t * (HEADS * KNN) + tid];
    }
    __syncthreads();

    const float* drow = qd + (size_t)t * NC;
    const float* rrow = resid + (size_t)t * VDIM;
    float acc[3];
#pragma unroll
    for (int j = 0; j < 3; ++j) {
        int d = tid + j * 256;
        acc[j] = drow[d] + rrow[d];
    }
    for (int p = 0; p < HEADS * KNN; ++p) {
        float w = ws[p];
        const float* vrow = values + (size_t)is_[p] * VDIM;
#pragma unroll
        for (int j = 0; j < 3; ++j)
            acc[j] = fmaf(w, vrow[tid + j * 256], acc[j]);
    }
    float s  = acc[0] + acc[1] + acc[2];
    float s2 = acc[0] * acc[0] + acc[1] * acc[1] + acc[2] * acc[2];
#pragma unroll
    for (int m = 1; m < 64; m <<= 1) { s += __shfl_xor(s, m); s2 += __shfl_xor(s2, m); }
    if (lane == 0) { red[wave] = s; red[4 + wave] = s2; }
    __syncthreads();
    s  = red[0] + red[1] + red[2] + red[3];
    s2 = red[4] + red[5] + red[6] + red[7];
    const float mu  = s * (1.f / VDIM);
    const float var = s2 * (1.f / VDIM) - mu * mu;
    const float inv = rsqrtf(var + 1e-12f);
#pragma unroll
    for (int j = 0; j < 3; ++j) {
        int d = tid + j * 256;
        out[(size_t)t * VDIM + d] = (acc[j] - mu) * inv * gamma[d] + beta[d];
    }
}

// ---------------------------------------------------------------------------
extern "C" void kernel_launch(void* const* d_in, const int* in_sizes, int n_in,
                              void* d_out, int out_size, void* d_ws, size_t ws_size,
                              hipStream_t stream) {
    const float* x      = (const float*)d_in[0];  // (B*S, 3072) fp32
    const float* resid  = (const float*)d_in[1];  // (B*S, 768)
    const float* Wd     = (const float*)d_in[2];  // (3072, 768)
    const float* bd     = (const float*)d_in[3];  // (768,)
    const float* Wq     = (const float*)d_in[4];  // (3072, 1024)
    const float* bq     = (const float*)d_in[5];  // (1024,)
    const float* keys   = (const float*)d_in[6];  // (4,2,128,128)
    const float* values = (const float*)d_in[7];  // (16384, 768)
    const float* gamma  = (const float*)d_in[8];
    const float* beta   = (const float*)d_in[9];
    float* out = (float*)d_out;                    // fp32 output

    const int M = in_sizes[0] / INDIM;   // 16384

    // workspace layout
    uint8_t* w = (uint8_t*)d_ws;
    const size_t szXb = (size_t)M * INDIM * sizeof(__hip_bfloat16);    // 100.7 MB
    const size_t szWc = (size_t)NC * INDIM * sizeof(__hip_bfloat16);   // 11.0 MB
    const size_t szQd = (size_t)M * NC * sizeof(float);                // 117.4 MB
    const size_t szPw = (size_t)M * HEADS * KNN * sizeof(float);       // 8.4 MB
    const size_t szPi = (size_t)M * HEADS * KNN * sizeof(int);         // 8.4 MB
    if (szXb + szWc + szQd + szPw + szPi > ws_size) return;  // leaves zeros: absmax==5.21875 signal
    __hip_bfloat16* xb = (__hip_bfloat16*)w;           w += szXb;
    __hip_bfloat16* Wc = (__hip_bfloat16*)w;           w += szWc;
    float*          qd = (float*)w;                    w += szQd;
    float*          pw = (float*)w;                    w += szPw;
    int*            pi = (int*)w;                      w += szPi;

    const int n8 = (M * INDIM) / 8;
    convert_bf16<<<(n8 + 255) / 256, 256, 0, stream>>>(x, xb, n8);
    transpose_w<<<dim3(INDIM / 32, NC / 32), dim3(32, 8), 0, stream>>>(Wd, Wq, Wc);
    gemm_bt<<<dim3(M / 128, NC / 128), 256, 0, stream>>>(xb, Wc, bd, bq, qd, M);
    pkm_select<<<M, 256, 0, stream>>>(qd, keys, pw, pi);
    fuse_ln<<<M, 256, 0, stream>>>(qd, resid, values, pw, pi, gamma, beta, out);
}

// Round 4
// 2322.911 us; speedup vs baseline: 2.7988x; 2.7988x over previous
//
#include <hip/hip_runtime.h>
#include <hip/hip_bf16.h>
#include <stdint.h>

// Problem constants (fixed by the reference)
#define HEADS 4
#define KNN   32
#define NKEYS 128
#define KDIM  256
#define VDIM  768
#define INDIM 3072
#define HALFD 128
#define NC    (VDIM + HEADS * KDIM)   // 1792 combined output cols: [dense(768) | q(1024)]

typedef __bf16 bf16x8 __attribute__((ext_vector_type(8)));
typedef short  short8 __attribute__((ext_vector_type(8)));
typedef float  f32x4  __attribute__((ext_vector_type(4)));

__device__ __forceinline__ void async_copy16(const void* g, void* l) {
    __builtin_amdgcn_global_load_lds((__attribute__((address_space(1))) void*)(g),
                                     (__attribute__((address_space(3))) void*)(l),
                                     16, 0, 0);
}

// Staircase candidate table: {(i,j) : (i+1)*(j+1) <= 32} in flat-index order.
// Monotone-matrix argument: any (i,j) outside has >= 32 dominators that all
// precede it in JAX's tie-break order => true top-32 is inside. 119 entries.
#define NCAND 119
struct CandT { unsigned char ii[128]; unsigned char jj[128]; };
static constexpr CandT make_cands() {
    CandT t{}; int c = 0;
    for (int i = 0; i < 32; ++i)
        for (int j = 0; (i + 1) * (j + 1) <= 32; ++j) {
            t.ii[c] = (unsigned char)i; t.jj[c] = (unsigned char)j; ++c;
        }
    for (; c < 128; ++c) { t.ii[c] = 0; t.jj[c] = 0; }
    return t;
}
static constexpr CandT CAND = make_cands();

// ---------------------------------------------------------------------------
// Kernel 0: fp32 -> bf16 convert for x (one thread per 8 elements)
// ---------------------------------------------------------------------------
__global__ __launch_bounds__(256) void convert_bf16(
    const float* __restrict__ in, __hip_bfloat16* __restrict__ out, int n8)
{
    int i = blockIdx.x * 256 + threadIdx.x;
    if (i >= n8) return;
    float4 a = ((const float4*)in)[2 * i + 0];
    float4 b = ((const float4*)in)[2 * i + 1];
    union { short8 v; __hip_bfloat16 h[8]; } u;
    u.h[0] = __float2bfloat16(a.x); u.h[1] = __float2bfloat16(a.y);
    u.h[2] = __float2bfloat16(a.z); u.h[3] = __float2bfloat16(a.w);
    u.h[4] = __float2bfloat16(b.x); u.h[5] = __float2bfloat16(b.y);
    u.h[6] = __float2bfloat16(b.z); u.h[7] = __float2bfloat16(b.w);
    ((short8*)out)[i] = u.v;
}

// ---------------------------------------------------------------------------
// Kernel 1: build Bt = [W_dense | W_q]^T as (NC x INDIM) bf16, via LDS tiles
// ---------------------------------------------------------------------------
__global__ __launch_bounds__(256) void transpose_w(
    const float* __restrict__ Wd,   // (3072, 768) fp32
    const float* __restrict__ Wq,   // (3072, 1024) fp32
    __hip_bfloat16* __restrict__ Wc)// (1792, 3072) bf16
{
    __shared__ float tile[32][33];
    const int kt = blockIdx.x * 32;
    const int nt = blockIdx.y * 32;
    const int tx = threadIdx.x;   // 0..31
    const int ty = threadIdx.y;   // 0..7
    const float* src;
    int ldn, ncol;
    if (nt < VDIM) { src = Wd; ldn = VDIM; ncol = nt; }
    else           { src = Wq; ldn = HEADS * KDIM; ncol = nt - VDIM; }
#pragma unroll
    for (int j = 0; j < 32; j += 8)
        tile[ty + j][tx] = src[(size_t)(kt + ty + j) * ldn + ncol + tx];
    __syncthreads();
#pragma unroll
    for (int j = 0; j < 32; j += 8)
        Wc[(size_t)(nt + ty + j) * INDIM + kt + tx] = __float2bfloat16(tile[tx][ty + j]);
}

// ---------------------------------------------------------------------------
// Kernel 2: C(M x 1792) = A(M x 3072) @ Bt^T + bias   (bf16 MFMA, m97 structure)
// ---------------------------------------------------------------------------
__global__ __launch_bounds__(256) void gemm_bt(
    const __hip_bfloat16* __restrict__ A,   // (M, 3072) bf16
    const __hip_bfloat16* __restrict__ Bt,  // (1792, 3072) bf16
    const float* __restrict__ bd,  // (768,) fp32
    const float* __restrict__ bq,  // (1024,) fp32
    float* __restrict__ C, int M)
{
    constexpr int K = INDIM, N = NC;
    __shared__ __align__(16) __hip_bfloat16 As[128 * 32];
    __shared__ __align__(16) __hip_bfloat16 Bs[128 * 32];
    const int tid  = threadIdx.x;
    const int wave = tid >> 6, lane = tid & 63;
    const int wm = wave >> 1, wn = wave & 1;
    const int row0 = blockIdx.x * 128, col0 = blockIdx.y * 128;

    const int fb0 = (wave * 2 + 0) * 1024;
    const int fb1 = (wave * 2 + 1) * 1024;
    const int r0  = (fb0 >> 6) + (lane >> 2);
    const int r1  = (fb1 >> 6) + (lane >> 2);
    const int ce  = (lane & 3) * 8;
    const __hip_bfloat16* gA0 = A  + (size_t)(row0 + r0) * K + ce;
    const __hip_bfloat16* gA1 = A  + (size_t)(row0 + r1) * K + ce;
    const __hip_bfloat16* gB0 = Bt + (size_t)(col0 + r0) * K + ce;
    const __hip_bfloat16* gB1 = Bt + (size_t)(col0 + r1) * K + ce;
    char* lA0 = (char*)As + fb0;  char* lA1 = (char*)As + fb1;
    char* lB0 = (char*)Bs + fb0;  char* lB1 = (char*)Bs + fb1;

    const int aoff = (wm * 64 + (lane & 15)) * 64 + (lane >> 4) * 16;
    const int boff = (wn * 64 + (lane & 15)) * 64 + (lane >> 4) * 16;

    f32x4 acc[4][4];
#pragma unroll
    for (int i = 0; i < 4; i++)
#pragma unroll
        for (int j = 0; j < 4; j++) acc[i][j] = (f32x4){0.f, 0.f, 0.f, 0.f};

    for (int k0 = 0; k0 < K; k0 += 32) {
        __syncthreads();
        async_copy16(gA0 + k0, lA0);
        async_copy16(gA1 + k0, lA1);
        async_copy16(gB0 + k0, lB0);
        async_copy16(gB1 + k0, lB1);
        __syncthreads();

        bf16x8 af[4], bfr[4];
#pragma unroll
        for (int i = 0; i < 4; i++)
            af[i] = *(const bf16x8*)((const char*)As + aoff + i * 1024);
#pragma unroll
        for (int j = 0; j < 4; j++)
            bfr[j] = *(const bf16x8*)((const char*)Bs + boff + j * 1024);
#pragma unroll
        for (int i = 0; i < 4; i++)
#pragma unroll
            for (int j = 0; j < 4; j++)
                acc[i][j] = __builtin_amdgcn_mfma_f32_16x16x32_bf16(af[i], bfr[j], acc[i][j], 0, 0, 0);
    }

    float bias[4]; int ncol[4];
#pragma unroll
    for (int j = 0; j < 4; j++) {
        int n = col0 + wn * 64 + j * 16 + (lane & 15);
        ncol[j] = n;
        bias[j] = (n < VDIM) ? bd[n] : bq[n - VDIM];
    }
#pragma unroll
    for (int i = 0; i < 4; i++) {
#pragma unroll
        for (int r = 0; r < 4; r++) {
            int m = row0 + wm * 64 + i * 16 + (lane >> 4) * 4 + r;
            float* crow = C + (size_t)m * N;
#pragma unroll
            for (int j = 0; j < 4; j++) crow[ncol[j]] = acc[i][j][r] + bias[j];
        }
    }
}

// ---------------------------------------------------------------------------
// Kernel 3: PKM scoring + rank-based two-stage top-k + softmax.
// One block per token; wave w = head h. Rank selection: no serial argmax.
// ---------------------------------------------------------------------------
__global__ __launch_bounds__(256) void pkm_select(
    const float* __restrict__ qd,    // (M, 1792); q at cols 768..1792
    const float* __restrict__ keys,  // (4, 2, 128, 128) fp32
    float* __restrict__ w_out,       // (M, 4, 32)
    int* __restrict__ i_out)         // (M, 4, 32)
{
    const int t = blockIdx.x;
    const int tid = threadIdx.x;
    const int h = tid >> 6, lane = tid & 63;

    __shared__ __align__(16) float qs[HEADS * KDIM];        // 4 KB
    __shared__ __align__(16) float sc[HEADS][2][NKEYS];     // 4 KB scores
    __shared__ float vsort[HEADS][2][KNN];                  // sorted top-32 vals
    __shared__ int   isort[HEADS][2][KNN];                  // sorted top-32 idxs
    __shared__ __align__(16) float csum[HEADS][128];        // candidate sums
    __shared__ float wsel[HEADS][KNN];
    __shared__ int   bsel[HEADS][KNN];

    // stage q (1024 floats, one float4 per thread)
    {
        const float4* qrow = (const float4*)(qd + (size_t)t * NC + VDIM);
        ((float4*)qs)[tid] = qrow[tid];
    }
    __syncthreads();

    // ---- scores: lane handles sub-keys n0=lane, n1=lane+64 for both halves
    const int n0 = lane, n1 = lane + 64;
    float v0[2], v1[2];
#pragma unroll
    for (int half = 0; half < 2; ++half) {
        const float* kb = keys + (size_t)((h * 2 + half) * NKEYS) * HALFD;
        const float* qh = qs + h * KDIM + half * HALFD;
        const float* kr0 = kb + (size_t)n0 * HALFD;
        const float* kr1 = kb + (size_t)n1 * HALFD;
        float a0 = 0.f, a1 = 0.f;
#pragma unroll 4
        for (int d = 0; d < HALFD; d += 4) {
            float4 qv = *(const float4*)(qh + d);     // LDS broadcast
            float4 k0 = *(const float4*)(kr0 + d);
            float4 k1 = *(const float4*)(kr1 + d);
            a0 = fmaf(k0.x, qv.x, a0); a0 = fmaf(k0.y, qv.y, a0);
            a0 = fmaf(k0.z, qv.z, a0); a0 = fmaf(k0.w, qv.w, a0);
            a1 = fmaf(k1.x, qv.x, a1); a1 = fmaf(k1.y, qv.y, a1);
            a1 = fmaf(k1.z, qv.z, a1); a1 = fmaf(k1.w, qv.w, a1);
        }
        sc[h][half][n0] = a0;
        sc[h][half][n1] = a1;
        v0[half] = a0; v1[half] = a1;
    }
    __syncthreads();

    // ---- stage 1: rank-select top-32 of 128 per half (ties -> lower index,
    //      exactly jax.lax.top_k order); scatter into sorted lists.
#pragma unroll
    for (int half = 0; half < 2; ++half) {
        const float4* scv = (const float4*)&sc[h][half][0];
        const float a0 = v0[half], a1 = v1[half];
        int r0 = 0, r1 = 0;
#pragma unroll
        for (int g4 = 0; g4 < 32; ++g4) {
            float4 e = scv[g4];                       // broadcast read
            int gb = g4 * 4;
            r0 += (e.x > a0) || (e.x == a0 && (gb + 0) < n0);
            r0 += (e.y > a0) || (e.y == a0 && (gb + 1) < n0);
            r0 += (e.z > a0) || (e.z == a0 && (gb + 2) < n0);
            r0 += (e.w > a0) || (e.w == a0 && (gb + 3) < n0);
            r1 += (e.x > a1) || (e.x == a1 && (gb + 0) < n1);
            r1 += (e.y > a1) || (e.y == a1 && (gb + 1) < n1);
            r1 += (e.z > a1) || (e.z == a1 && (gb + 2) < n1);
            r1 += (e.w > a1) || (e.w == a1 && (gb + 3) < n1);
        }
        if (r0 < KNN) { vsort[h][half][r0] = a0; isort[h][half][r0] = n0; }
        if (r1 < KNN) { vsort[h][half][r1] = a1; isort[h][half][r1] = n1; }
    }
    __syncthreads();

    // ---- stage 2: staircase candidates (sorted lists => exact top-32 superset)
    const int c0 = lane, c1 = lane + 64;
    float s0, s1 = -1e30f;
    int b0, b1 = 0;
    {
        int i0 = CAND.ii[c0], j0 = CAND.jj[c0];
        s0 = vsort[h][0][i0] + vsort[h][1][j0];
        b0 = isort[h][0][i0] * NKEYS + isort[h][1][j0];
    }
    if (c1 < NCAND) {
        int i1 = CAND.ii[c1], j1 = CAND.jj[c1];
        s1 = vsort[h][0][i1] + vsort[h][1][j1];
        b1 = isort[h][0][i1] * NKEYS + isort[h][1][j1];
    }
    csum[h][c0] = s0;
    csum[h][c1] = s1;
    __syncthreads();

    // rank among 128 candidates (ties -> lower candidate index == lower flat idx)
    {
        const float4* cs4 = (const float4*)&csum[h][0];
        int r0 = 0, r1 = 0;
#pragma unroll
        for (int g4 = 0; g4 < 32; ++g4) {
            float4 e = cs4[g4];
            int gb = g4 * 4;
            r0 += (e.x > s0) || (e.x == s0 && (gb + 0) < c0);
            r0 += (e.y > s0) || (e.y == s0 && (gb + 1) < c0);
            r0 += (e.z > s0) || (e.z == s0 && (gb + 2) < c0);
            r0 += (e.w > s0) || (e.w == s0 && (gb + 3) < c0);
            r1 += (e.x > s1) || (e.x == s1 && (gb + 0) < c1);
            r1 += (e.y > s1) || (e.y == s1 && (gb + 1) < c1);
            r1 += (e.z > s1) || (e.z == s1 && (gb + 2) < c1);
            r1 += (e.w > s1) || (e.w == s1 && (gb + 3) < c1);
        }
        if (r0 < KNN) { wsel[h][r0] = s0; bsel[h][r0] = b0; }
        if (r1 < KNN) { wsel[h][r1] = s1; bsel[h][r1] = b1; }
    }
    __syncthreads();

    // ---- softmax over the 32 selected (lanes 0..31)
    if (lane < KNN) {
        float v = wsel[h][lane];
        float mx = v;
#pragma unroll
        for (int m = 16; m >= 1; m >>= 1) mx = fmaxf(mx, __shfl_xor(mx, m));
        float e = expf(v - mx);
        float sum = e;
#pragma unroll
        for (int m = 16; m >= 1; m >>= 1) sum += __shfl_xor(sum, m);
        size_t o = ((size_t)t * HEADS + h) * KNN + lane;
        w_out[o] = e / sum;
        i_out[o] = bsel[h][lane];
    }
}

// ---------------------------------------------------------------------------
// Kernel 4: value gather + dense + residual + layernorm. One block per token.
// Output is fp32 (reference output dtype).
// ---------------------------------------------------------------------------
__global__ __launch_bounds__(256) void fuse_ln(
    const float* __restrict__ qd,              // dense at cols 0..768 (bias included)
    const float* __restrict__ resid,           // (M, 768) fp32
    const float* __restrict__ values,          // (16384, 768) fp32
    const float* __restrict__ pw, const int* __restrict__ pi,  // (M,128)
    const float* __restrict__ gamma, const float* __restrict__ beta,
    float* __restrict__ out)
{
    const int t = blockIdx.x, tid = threadIdx.x;
    const int wave = tid >> 6, lane = tid & 63;
    __shared__ float ws[HEADS * KNN];
    __shared__ int   is_[HEADS * KNN];
    __shared__ float red[8];
    if (tid < HEADS * KNN) {
        ws[tid]  = pw[(size_t)t * (HEADS * KNN) + tid];
        is_[tid] = pi[(size_t)t * (HEADS * KNN) + tid];
    }
    __syncthreads();

    const float* drow = qd + (size_t)t * NC;
    const float* rrow = resid + (size_t)t * VDIM;
    float acc[3];
#pragma unroll
    for (int j = 0; j < 3; ++j) {
        int d = tid + j * 256;
        acc[j] = drow[d] + rrow[d];
    }
    for (int p = 0; p < HEADS * KNN; ++p) {
        float w = ws[p];
        const float* vrow = values + (size_t)is_[p] * VDIM;
#pragma unroll
        for (int j = 0; j < 3; ++j)
            acc[j] = fmaf(w, vrow[tid + j * 256], acc[j]);
    }
    float s  = acc[0] + acc[1] + acc[2];
    float s2 = acc[0] * acc[0] + acc[1] * acc[1] + acc[2] * acc[2];
#pragma unroll
    for (int m = 1; m < 64; m <<= 1) { s += __shfl_xor(s, m); s2 += __shfl_xor(s2, m); }
    if (lane == 0) { red[wave] = s; red[4 + wave] = s2; }
    __syncthreads();
    s  = red[0] + red[1] + red[2] + red[3];
    s2 = red[4] + red[5] + red[6] + red[7];
    const float mu  = s * (1.f / VDIM);
    const float var = s2 * (1.f / VDIM) - mu * mu;
    const float inv = rsqrtf(var + 1e-12f);
#pragma unroll
    for (int j = 0; j < 3; ++j) {
        int d = tid + j * 256;
        out[(size_t)t * VDIM + d] = (acc[j] - mu) * inv * gamma[d] + beta[d];
    }
}

// ---------------------------------------------------------------------------
extern "C" void kernel_launch(void* const* d_in, const int* in_sizes, int n_in,
                              void* d_out, int out_size, void* d_ws, size_t ws_size,
                              hipStream_t stream) {
    const float* x      = (const float*)d_in[0];  // (B*S, 3072) fp32
    const float* resid  = (const float*)d_in[1];  // (B*S, 768)
    const float* Wd     = (const float*)d_in[2];  // (3072, 768)
    const float* bd     = (const float*)d_in[3];  // (768,)
    const float* Wq     = (const float*)d_in[4];  // (3072, 1024)
    const float* bq     = (const float*)d_in[5];  // (1024,)
    const float* keys   = (const float*)d_in[6];  // (4,2,128,128)
    const float* values = (const float*)d_in[7];  // (16384, 768)
    const float* gamma  = (const float*)d_in[8];
    const float* beta   = (const float*)d_in[9];
    float* out = (float*)d_out;                    // fp32 output

    const int M = in_sizes[0] / INDIM;   // 16384

    // workspace layout
    uint8_t* w = (uint8_t*)d_ws;
    const size_t szXb = (size_t)M * INDIM * sizeof(__hip_bfloat16);    // 100.7 MB
    const size_t szWc = (size_t)NC * INDIM * sizeof(__hip_bfloat16);   // 11.0 MB
    const size_t szQd = (size_t)M * NC * sizeof(float);                // 117.4 MB
    const size_t szPw = (size_t)M * HEADS * KNN * sizeof(float);       // 8.4 MB
    const size_t szPi = (size_t)M * HEADS * KNN * sizeof(int);         // 8.4 MB
    if (szXb + szWc + szQd + szPw + szPi > ws_size) return;
    __hip_bfloat16* xb = (__hip_bfloat16*)w;           w += szXb;
    __hip_bfloat16* Wc = (__hip_bfloat16*)w;           w += szWc;
    float*          qd = (float*)w;                    w += szQd;
    float*          pw = (float*)w;                    w += szPw;
    int*            pi = (int*)w;                      w += szPi;

    const int n8 = (M * INDIM) / 8;
    convert_bf16<<<(n8 + 255) / 256, 256, 0, stream>>>(x, xb, n8);
    transpose_w<<<dim3(INDIM / 32, NC / 32), dim3(32, 8), 0, stream>>>(Wd, Wq, Wc);
    gemm_bt<<<dim3(M / 128, NC / 128), 256, 0, stream>>>(xb, Wc, bd, bq, qd, M);
    pkm_select<<<M, 256, 0, stream>>>(qd, keys, pw, pi);
    fuse_ln<<<M, 256, 0, stream>>>(qd, resid, values, pw, pi, gamma, beta, out);
}